// Round 5
// baseline (127627.612 us; speedup 1.0000x reference)
//
#include <hip/hip_runtime.h>
#include <math.h>

// Problem constants
#define D_   512
#define NH   8
#define BQ   512
#define SS   48
#define QQ   12
#define LL   4
#define MMAX (BQ * QQ)        // 6144 max rows

typedef __attribute__((ext_vector_type(8))) short s16x8;
typedef __attribute__((ext_vector_type(4))) float f32x4;
typedef unsigned short u16;

__device__ __forceinline__ u16 f2bf(float x) {
    union { float f; unsigned u; } v; v.f = x;
    unsigned r = v.u + 0x7fffu + ((v.u >> 16) & 1u);
    return (u16)(r >> 16);
}
__device__ __forceinline__ float bf2f(u16 b) {
    union { float f; unsigned u; } v; v.u = ((unsigned)b) << 16;
    return v.f;
}

// packed-weight geometry (ushort units)
#define QKV_SZ   (3 * 64 * 1536 * 8)
#define CAQ_OFF  QKV_SZ
#define CAKV_OFF (CAQ_OFF + 3 * 64 * 512 * 8)
#define SAO_OFF  (CAKV_OFF + 3 * 64 * 1024 * 8)
#define CAO_OFF  (SAO_OFF + 3 * 64 * 512 * 8)
#define F1_OFF   (CAO_OFF + 3 * 64 * 512 * 8)
#define F2_OFF   (F1_OFF + 3 * 64 * 512 * 8)
#define LPACK    (F2_OFF + 3 * 64 * 512 * 8)   // 7,864,320 ushorts / layer

// ---------------------------------------------------------------------------
// Manual grid-wide barrier (sense-reversing, agent-scope atomics + fences).
// Requires all blocks resident: grid = 2*numCU, LB(256,2), 48KB LDS.
// ---------------------------------------------------------------------------
__device__ __forceinline__ void grid_barrier(unsigned* cnt, unsigned* gen, unsigned nblk)
{
    __syncthreads();
    if (threadIdx.x == 0) {
        __threadfence();   // agent-scope release of this block's writes
        unsigned g = __hip_atomic_load(gen, __ATOMIC_RELAXED, __HIP_MEMORY_SCOPE_AGENT);
        unsigned a = __hip_atomic_fetch_add(cnt, 1u, __ATOMIC_ACQ_REL, __HIP_MEMORY_SCOPE_AGENT);
        if (a == nblk - 1u) {
            __hip_atomic_store(cnt, 0u, __ATOMIC_RELAXED, __HIP_MEMORY_SCOPE_AGENT);
            __hip_atomic_store(gen, g + 1u, __ATOMIC_RELEASE, __HIP_MEMORY_SCOPE_AGENT);
        } else {
            while (__hip_atomic_load(gen, __ATOMIC_ACQUIRE, __HIP_MEMORY_SCOPE_AGENT) == g)
                __builtin_amdgcn_s_sleep(2);
        }
        __threadfence();   // agent-scope acquire side
    }
    __syncthreads();
}

// ---------------------------------------------------------------------------
// Pre-pack weights: W[l](512 k x N cols) fp32 -> 3-split bf16 [s][g][n][8k]
// ---------------------------------------------------------------------------
__global__ __launch_bounds__(256)
void pack_weights(const float* __restrict__ s0, const float* __restrict__ s1,
                  const float* __restrict__ s2, const float* __restrict__ s3,
                  const float* __restrict__ s4, const float* __restrict__ s5,
                  const float* __restrict__ s6, const float* __restrict__ s7,
                  const float* __restrict__ s8, const float* __restrict__ s9,
                  u16* __restrict__ PACK)
{
    const int id    = blockIdx.y;       // 0..39
    const int mat   = id >> 2;
    const int layer = id & 3;
    const int idx   = blockIdx.x * 256 + threadIdx.x;   // 0..32767
    const int n     = idx & 511;
    const int g     = idx >> 9;         // k-group 0..63

    const float* srcs[10] = {s0, s1, s2, s3, s4, s5, s6, s7, s8, s9};
    const int dstoff[10] = {0, 0, 0, CAQ_OFF, CAKV_OFF, CAKV_OFF,
                            SAO_OFF, CAO_OFF, F1_OFF, F2_OFF};
    const int ntot[10] = {1536, 1536, 1536, 512, 1024, 1024, 512, 512, 512, 512};
    const int noff[10] = {0, 512, 1024, 0, 0, 512, 0, 0, 0, 0};

    const float* src = srcs[mat] + (size_t)layer * 512 * 512;
    const int Ntot = ntot[mat];
    const size_t SPS = (size_t)64 * Ntot * 8;

    s16x8 vh, vm, vl;
#pragma unroll
    for (int e = 0; e < 8; ++e) {
        float x = src[(size_t)(g * 8 + e) * 512 + n];
        u16 hh = f2bf(x); float r = x - bf2f(hh);
        u16 mm = f2bf(r); r -= bf2f(mm);
        vh[e] = (short)hh; vm[e] = (short)mm; vl[e] = (short)f2bf(r);
    }
    u16* d = PACK + (size_t)layer * LPACK + dstoff[mat]
           + ((size_t)g * Ntot + noff[mat] + n) * 8;
    *(s16x8*)(d)           = vh;
    *(s16x8*)(d + SPS)     = vm;
    *(s16x8*)(d + 2 * SPS) = vl;
}

__global__ void pack_bias(const float* __restrict__ sbq, const float* __restrict__ sbk,
                          const float* __restrict__ sbv, const float* __restrict__ cbk,
                          const float* __restrict__ cbv, float* __restrict__ qkvb,
                          float* __restrict__ cakvb)
{
    int i = blockIdx.x * 256 + threadIdx.x;
    if (i < 4 * 1536) {
        int l = i / 1536, c = i - l * 1536;
        float v = (c < 512) ? sbq[l * 512 + c]
                : (c < 1024) ? sbk[l * 512 + c - 512] : sbv[l * 512 + c - 1024];
        qkvb[i] = v;
    } else if (i < 4 * 1536 + 4 * 1024) {
        int j = i - 4 * 1536;
        int l = j / 1024, c = j - l * 1024;
        cakvb[j] = (c < 512) ? cbk[l * 512 + c] : cbv[l * 512 + c - 512];
    }
}

// ---------------------------------------------------------------------------
// Mega-kernel args
// ---------------------------------------------------------------------------
struct MegaArgs {
    const float* x;
    float* out;
    unsigned* bar;
    float* pe; float* h; float* big; float* ta;
    const float* qkvb; const float* cakvb;
    const u16* PACK;
    float* kvc;
    const float *sa_bo, *ca_bq, *ca_bo, *ffn_b1, *ffn_b2;
    const float *ln1_g, *ln1_b, *ln2_g, *ln2_b, *ln3_g, *ln3_b;
    const float *dw, *db;
    int use_cache;
};

// ---------------------------------------------------------------------------
// GEMM stage: grid-strided 128x128 tiles, 3-split bf16 MFMA.
// 256 thr = 4 waves, each 64x64, 4x4 frags, BK=32, XOR-swizzled LDS.
// ---------------------------------------------------------------------------
__device__ __forceinline__
void gemm_tiles(const float* __restrict__ A, const u16* __restrict__ PW,
                const float* __restrict__ bias, float* __restrict__ C,
                int M, int N, int relu, unsigned char* smem)
{
    u16 (*As)[4096] = reinterpret_cast<u16 (*)[4096]>(smem);
    u16 (*Bs)[4096] = reinterpret_cast<u16 (*)[4096]>(smem + 24576);

    const int tid = threadIdx.x;
    const int l  = tid & 63;
    const int wv = tid >> 6;
    const int wm = (wv >> 1) * 64, wn = (wv & 1) * 64;
    const int r0 = tid >> 2, g0 = tid & 3;
    const int eo0 = ((r0 * 32 + g0 * 8) ^ ((r0 & 7) << 3));
    const int eo1 = eo0 + 64 * 32;
    const size_t SPS = (size_t)64 * N * 8;
    const int nbn = N >> 7;
    const int tiles = (M >> 7) * nbn;

    for (int t = blockIdx.x; t < tiles; t += gridDim.x) {
        const int bm = t / nbn, bn = t - bm * nbn;

        f32x4 acc[4][4] = {};
        const float* a0 = A + (size_t)(bm * 128 + r0) * 512 + g0 * 8;
        const float* a1 = a0 + (size_t)64 * 512;

        for (int ks = 0; ks < 16; ++ks) {
            const int k0 = ks * 32;
            float4 av00 = *(const float4*)(a0 + k0);
            float4 av01 = *(const float4*)(a0 + k0 + 4);
            float4 av10 = *(const float4*)(a1 + k0);
            float4 av11 = *(const float4*)(a1 + k0 + 4);
            const u16* pb = PW + ((size_t)((k0 >> 3) + g0) * N + bn * 128 + r0) * 8;
            s16x8 b00 = *(const s16x8*)(pb);
            s16x8 b01 = *(const s16x8*)(pb + SPS);
            s16x8 b02 = *(const s16x8*)(pb + 2 * SPS);
            s16x8 b10 = *(const s16x8*)(pb + (size_t)64 * 8);
            s16x8 b11 = *(const s16x8*)(pb + (size_t)64 * 8 + SPS);
            s16x8 b12 = *(const s16x8*)(pb + (size_t)64 * 8 + 2 * SPS);

            __syncthreads();   // prior frag reads (or prior tile) done

            {
                float va[8] = {av00.x, av00.y, av00.z, av00.w, av01.x, av01.y, av01.z, av01.w};
                s16x8 vh, vm2, vl2;
#pragma unroll
                for (int e = 0; e < 8; ++e) {
                    u16 hh = f2bf(va[e]); float r = va[e] - bf2f(hh);
                    u16 mm = f2bf(r); r -= bf2f(mm);
                    vh[e] = (short)hh; vm2[e] = (short)mm; vl2[e] = (short)f2bf(r);
                }
                *(s16x8*)&As[0][eo0] = vh; *(s16x8*)&As[1][eo0] = vm2; *(s16x8*)&As[2][eo0] = vl2;
            }
            {
                float va[8] = {av10.x, av10.y, av10.z, av10.w, av11.x, av11.y, av11.z, av11.w};
                s16x8 vh, vm2, vl2;
#pragma unroll
                for (int e = 0; e < 8; ++e) {
                    u16 hh = f2bf(va[e]); float r = va[e] - bf2f(hh);
                    u16 mm = f2bf(r); r -= bf2f(mm);
                    vh[e] = (short)hh; vm2[e] = (short)mm; vl2[e] = (short)f2bf(r);
                }
                *(s16x8*)&As[0][eo1] = vh; *(s16x8*)&As[1][eo1] = vm2; *(s16x8*)&As[2][eo1] = vl2;
            }
            *(s16x8*)&Bs[0][eo0] = b00; *(s16x8*)&Bs[1][eo0] = b01; *(s16x8*)&Bs[2][eo0] = b02;
            *(s16x8*)&Bs[0][eo1] = b10; *(s16x8*)&Bs[1][eo1] = b11; *(s16x8*)&Bs[2][eo1] = b12;

            __syncthreads();

            s16x8 af[3][4];
#pragma unroll
            for (int i = 0; i < 4; ++i) {
                int row = wm + i * 16 + (l & 15);
                int eo  = ((row * 32 + (l >> 4) * 8) ^ ((row & 7) << 3));
                af[0][i] = *(const s16x8*)&As[0][eo];
                af[1][i] = *(const s16x8*)&As[1][eo];
                af[2][i] = *(const s16x8*)&As[2][eo];
            }
#pragma unroll
            for (int j = 0; j < 4; ++j) {
                int nn = wn + j * 16 + (l & 15);
                int eo = ((nn * 32 + (l >> 4) * 8) ^ ((nn & 7) << 3));
                s16x8 bf0 = *(const s16x8*)&Bs[0][eo];
                s16x8 bf1 = *(const s16x8*)&Bs[1][eo];
                s16x8 bf2 = *(const s16x8*)&Bs[2][eo];
#pragma unroll
                for (int i = 0; i < 4; ++i) {
                    acc[i][j] = __builtin_amdgcn_mfma_f32_16x16x32_bf16(af[0][i], bf0, acc[i][j], 0, 0, 0);
                    acc[i][j] = __builtin_amdgcn_mfma_f32_16x16x32_bf16(af[0][i], bf1, acc[i][j], 0, 0, 0);
                    acc[i][j] = __builtin_amdgcn_mfma_f32_16x16x32_bf16(af[1][i], bf0, acc[i][j], 0, 0, 0);
                    acc[i][j] = __builtin_amdgcn_mfma_f32_16x16x32_bf16(af[0][i], bf2, acc[i][j], 0, 0, 0);
                    acc[i][j] = __builtin_amdgcn_mfma_f32_16x16x32_bf16(af[1][i], bf1, acc[i][j], 0, 0, 0);
                    acc[i][j] = __builtin_amdgcn_mfma_f32_16x16x32_bf16(af[2][i], bf0, acc[i][j], 0, 0, 0);
                }
            }
        }

#pragma unroll
        for (int i = 0; i < 4; ++i) {
            int row = bm * 128 + wm + i * 16 + (l >> 4) * 4;
#pragma unroll
            for (int j = 0; j < 4; ++j) {
                int col = bn * 128 + wn + j * 16 + (l & 15);
                float bb = bias[col];
#pragma unroll
                for (int r = 0; r < 4; ++r) {
                    float v = acc[i][j][r] + bb;
                    if (relu) v = fmaxf(v, 0.f);
                    C[(size_t)(row + r) * N + col] = v;
                }
            }
        }
    }
}

// ---------------------------------------------------------------------------
// Attention stage: grid-strided (batch,head) pairs.
// ---------------------------------------------------------------------------
__device__ __forceinline__
void attn_tiles(const float* __restrict__ Qb, int qstride,
                const float* __restrict__ Kb, const float* __restrict__ Vb, int kvstride,
                float* __restrict__ O, int Tq, int Tk, unsigned char* smem)
{
    float (*Qs)[65] = (float (*)[65])(smem);            // 3120 B
    float (*Ks)[65] = (float (*)[65])(smem + 3200);     // 12480 B
    float (*Vs)[65] = (float (*)[65])(smem + 16000);    // 12480 B
    float (*Sc)[49] = (float (*)[49])(smem + 28800);    // 2352 B

    const int tid = threadIdx.x;

    for (int p = blockIdx.x; p < BQ * NH; p += gridDim.x) {
        const int b = p >> 3;
        const int h = p & 7;

        const float* qb = Qb + (size_t)b * Tq * qstride + h * 64;
        const float* kb = Kb + (size_t)b * Tk * kvstride + h * 64;
        const float* vb = Vb + (size_t)b * Tk * kvstride + h * 64;

        for (int i = tid; i < Tq * 64; i += 256)
            Qs[i >> 6][i & 63] = qb[(size_t)(i >> 6) * qstride + (i & 63)];
        for (int i = tid; i < Tk * 64; i += 256) {
            Ks[i >> 6][i & 63] = kb[(size_t)(i >> 6) * kvstride + (i & 63)];
            Vs[i >> 6][i & 63] = vb[(size_t)(i >> 6) * kvstride + (i & 63)];
        }
        __syncthreads();

        for (int s = tid; s < Tq * Tk; s += 256) {
            int tq = s / Tk, tk = s - tq * Tk;
            float dot = 0.f;
#pragma unroll 16
            for (int c = 0; c < 64; ++c) dot = fmaf(Qs[tq][c], Ks[tk][c], dot);
            Sc[tq][tk] = dot * 0.125f;
        }
        __syncthreads();

        if (tid < Tq) {
            float mx = -1e30f;
            for (int tk = 0; tk < Tk; ++tk) mx = fmaxf(mx, Sc[tid][tk]);
            float sum = 0.f;
            for (int tk = 0; tk < Tk; ++tk) {
                float e = expf(Sc[tid][tk] - mx);
                Sc[tid][tk] = e; sum += e;
            }
            float inv = 1.f / sum;
            for (int tk = 0; tk < Tk; ++tk) Sc[tid][tk] *= inv;
        }
        __syncthreads();

        for (int o = tid; o < Tq * 64; o += 256) {
            int tq = o >> 6, c = o & 63;
            float acc = 0.f;
            for (int tk = 0; tk < Tk; ++tk) acc = fmaf(Sc[tq][tk], Vs[tk][c], acc);
            O[((size_t)b * Tq + tq) * 512 + h * 64 + c] = acc;
        }
        __syncthreads();   // LDS reuse by next pair
    }
}

// ---------------------------------------------------------------------------
// Residual + LayerNorm stage: grid-strided rows.
// ---------------------------------------------------------------------------
__device__ __forceinline__
void addln_tiles(const float* __restrict__ Ain, const float* __restrict__ Hin,
                 float* __restrict__ Out, const float* __restrict__ g,
                 const float* __restrict__ bt, int M, unsigned char* smem)
{
    float* red = (float*)smem;
    const int tid = threadIdx.x;

    for (int r = blockIdx.x; r < M; r += gridDim.x) {
        const size_t base = (size_t)r * 512 + tid;
        float v0 = Ain[base] + Hin[base];
        float v1 = Ain[base + 256] + Hin[base + 256];

        red[tid] = v0 + v1;
        __syncthreads();
        for (int off = 128; off > 0; off >>= 1) {
            if (tid < off) red[tid] += red[tid + off];
            __syncthreads();
        }
        float mu = red[0] * (1.f / 512.f);
        __syncthreads();

        float d0 = v0 - mu, d1 = v1 - mu;
        red[tid] = d0 * d0 + d1 * d1;
        __syncthreads();
        for (int off = 128; off > 0; off >>= 1) {
            if (tid < off) red[tid] += red[tid + off];
            __syncthreads();
        }
        float var = red[0] * (1.f / 512.f);
        float rs  = rsqrtf(var + 1e-6f);

        Out[base]       = d0 * rs * g[tid]       + bt[tid];
        Out[base + 256] = d1 * rs * g[tid + 256] + bt[tid + 256];
        __syncthreads();   // red[] reuse by next row
    }
}

// ---------------------------------------------------------------------------
// Mega-kernel: whole decoder in one launch, manual grid barrier.
// ---------------------------------------------------------------------------
__global__ __launch_bounds__(256, 2)
void mega(MegaArgs a)
{
    __shared__ __align__(16) unsigned char smem[49152];

    const int tid  = threadIdx.x;
    const int gtid = blockIdx.x * 256 + tid;
    const int gsz  = gridDim.x * 256;
    const unsigned nblk = gridDim.x;
    unsigned* bcnt = a.bar;
    unsigned* bgen = a.bar + 1;

#define GSYNC() grid_barrier(bcnt, bgen, nblk)

    // stage: positional-encoding table
    for (int i = gtid; i < QQ * D_; i += gsz) {
        int pos = i >> 9, dim = i & 511;
        float e   = 2.f * (float)(dim >> 1) / 512.f;
        float ang = (float)pos / powf(10000.f, e);
        a.pe[i] = (dim & 1) ? cosf(ang) : sinf(ang);
    }
    GSYNC();

    // stage: cross-attention KV cache (once per layer, not per q-step)
    if (a.use_cache) {
        for (int l = 0; l < LL; ++l)
            gemm_tiles(a.x, a.PACK + (size_t)l * LPACK + CAKV_OFF, a.cakvb + l * 1024,
                       a.kvc + (size_t)l * BQ * SS * 1024, BQ * SS, 1024, 0, smem);
        GSYNC();
    }

    for (int q = 0; q < QQ; ++q) {
        const int T = q + 1;
        const int M = BQ * T;

        // build h = shifted-out + pe
        for (size_t i = gtid; i < (size_t)M * 512; i += gsz) {
            int c = (int)(i & 511);
            size_t row = i >> 9;
            int t = (int)(row % T);
            size_t b = row / T;
            float y = (t == 0) ? 0.f : a.out[(b * QQ + (t - 1)) * 512 + c];
            a.h[i] = y + a.pe[t * 512 + c];
        }
        GSYNC();

        for (int ll = 0; ll < LL; ++ll) {
            const u16* wbase = a.PACK + (size_t)ll * LPACK;
            float* tt1 = a.big;
            float* tt2 = a.big + (size_t)MMAX * 512;
            float* ttq = a.big + (size_t)2 * MMAX * 512;
            float* kvl = a.use_cache ? (a.kvc + (size_t)ll * BQ * SS * 1024) : a.kvc;

            for (int st = 0; st < 12; ++st) {
                int mode = 3;                      // 0 gemm, 1 attn, 2 ln, 3 skip
                const float *gA = nullptr, *gb = nullptr;
                const u16* gW = nullptr; float* gC = nullptr;
                int gN = 512, grelu = 0, gM = M;
                const float *aQ = nullptr, *aK = nullptr, *aV = nullptr;
                int aqs = 0, akvs = 0, aTk = 0;
                const float *lg = nullptr, *lb = nullptr;

                switch (st) {
                    case 0:  mode = 0; gA = a.h;  gW = wbase;            gb = a.qkvb + ll * 1536; gC = a.big; gN = 1536; break;
                    case 1:  mode = 1; aQ = a.big; aqs = 1536; aK = a.big + 512; aV = a.big + 1024; akvs = 1536; aTk = T; break;
                    case 2:  mode = 0; gA = a.ta; gW = wbase + SAO_OFF;  gb = a.sa_bo + ll * 512; gC = tt1; break;
                    case 3:  mode = 2; lg = a.ln1_g + ll * 512; lb = a.ln1_b + ll * 512; break;
                    case 4:  mode = 0; gA = a.h;  gW = wbase + CAQ_OFF;  gb = a.ca_bq + ll * 512; gC = ttq; break;
                    case 5:  if (!a.use_cache) { mode = 0; gA = a.x; gW = wbase + CAKV_OFF;
                                                 gb = a.cakvb + ll * 1024; gC = kvl; gN = 1024; gM = BQ * SS; }
                             break;
                    case 6:  mode = 1; aQ = ttq; aqs = 512; aK = kvl; aV = kvl + 512; akvs = 1024; aTk = SS; break;
                    case 7:  mode = 0; gA = a.ta; gW = wbase + CAO_OFF;  gb = a.ca_bo + ll * 512; gC = tt1; break;
                    case 8:  mode = 2; lg = a.ln2_g + ll * 512; lb = a.ln2_b + ll * 512; break;
                    case 9:  mode = 0; gA = a.h;  gW = wbase + F1_OFF;   gb = a.ffn_b1 + ll * 512; gC = tt2; grelu = 1; break;
                    case 10: mode = 0; gA = tt2;  gW = wbase + F2_OFF;   gb = a.ffn_b2 + ll * 512; gC = tt1; break;
                    case 11: mode = 2; lg = a.ln3_g + ll * 512; lb = a.ln3_b + ll * 512; break;
                }

                if (mode == 0)      gemm_tiles(gA, gW, gb, gC, gM, gN, grelu, smem);
                else if (mode == 1) attn_tiles(aQ, aqs, aK, aV, akvs, a.ta, T, aTk, smem);
                else if (mode == 2) addln_tiles(tt1, a.h, a.h, lg, lb, M, smem);
                if (mode != 3) GSYNC();
            }
        }

        // dense combine -> out[:, q, :]
        for (size_t i = gtid; i < (size_t)BQ * 512; i += gsz) {
            int c = (int)(i & 511);
            size_t b = i >> 9;
            float acc = a.db[0];
            for (int n = 0; n < T; ++n) acc = fmaf(a.h[(b * T + n) * 512 + c], a.dw[n], acc);
            a.out[(b * QQ + q) * 512 + c] = acc;
        }
        GSYNC();
    }
#undef GSYNC
}

// ---------------------------------------------------------------------------
extern "C" void kernel_launch(void* const* d_in, const int* in_sizes, int n_in,
                              void* d_out, int out_size, void* d_ws, size_t ws_size,
                              hipStream_t stream)
{
    const float* x      = (const float*)d_in[0];
    const float* sa_wq  = (const float*)d_in[1];
    const float* sa_bq  = (const float*)d_in[2];
    const float* sa_wk  = (const float*)d_in[3];
    const float* sa_bk  = (const float*)d_in[4];
    const float* sa_wv  = (const float*)d_in[5];
    const float* sa_bv  = (const float*)d_in[6];
    const float* sa_wo  = (const float*)d_in[7];
    const float* sa_bo  = (const float*)d_in[8];
    const float* ca_wq  = (const float*)d_in[9];
    const float* ca_bq  = (const float*)d_in[10];
    const float* ca_wk  = (const float*)d_in[11];
    const float* ca_bk  = (const float*)d_in[12];
    const float* ca_wv  = (const float*)d_in[13];
    const float* ca_bv  = (const float*)d_in[14];
    const float* ca_wo  = (const float*)d_in[15];
    const float* ca_bo  = (const float*)d_in[16];
    const float* ffn_w1 = (const float*)d_in[17];
    const float* ffn_b1 = (const float*)d_in[18];
    const float* ffn_w2 = (const float*)d_in[19];
    const float* ffn_b2 = (const float*)d_in[20];
    const float* ln1_g  = (const float*)d_in[21];
    const float* ln1_b  = (const float*)d_in[22];
    const float* ln2_g  = (const float*)d_in[23];
    const float* ln2_b  = (const float*)d_in[24];
    const float* ln3_g  = (const float*)d_in[25];
    const float* ln3_b  = (const float*)d_in[26];
    const float* dw     = (const float*)d_in[27];
    const float* db     = (const float*)d_in[28];

    float* out = (float*)d_out;
    float* ws  = (float*)d_ws;

    // ws layout (float units)
    size_t off = 0;
    unsigned* bar = (unsigned*)ws; off += 4;               // barrier state (16B)
    float* pe    = ws + off; off += QQ * D_;
    float* h     = ws + off; off += (size_t)MMAX * 512;
    float* big   = ws + off; off += (size_t)MMAX * 1536;
    float* ta    = ws + off; off += (size_t)MMAX * 512;
    float* qkvb  = ws + off; off += 4 * 1536;
    float* cakvb = ws + off; off += 4 * 1024;
    off = (off + 3) & ~(size_t)3;
    u16* PACK = (u16*)(ws + off); off += (size_t)4 * LPACK / 2;
    float* kvc = ws + off;
    size_t full_need = off + (size_t)LL * BQ * SS * 1024;
    const int use_cache = (ws_size >= full_need * sizeof(float)) ? 1 : 0;

    // zero barrier state (ws is poisoned before every call)
    hipMemsetAsync(bar, 0, 4 * sizeof(unsigned), stream);

    pack_weights<<<dim3(128, 40), 256, 0, stream>>>(
        sa_wq, sa_wk, sa_wv, ca_wq, ca_wk, ca_wv, sa_wo, ca_wo, ffn_w1, ffn_w2, PACK);
    pack_bias<<<40, 256, 0, stream>>>(sa_bq, sa_bk, sa_bv, ca_bk, ca_bv, qkvb, cakvb);

    MegaArgs margs;
    margs.x = x; margs.out = out; margs.bar = bar;
    margs.pe = pe; margs.h = h; margs.big = big; margs.ta = ta;
    margs.qkvb = qkvb; margs.cakvb = cakvb;
    margs.PACK = PACK; margs.kvc = kvc;
    margs.sa_bo = sa_bo; margs.ca_bq = ca_bq; margs.ca_bo = ca_bo;
    margs.ffn_b1 = ffn_b1; margs.ffn_b2 = ffn_b2;
    margs.ln1_g = ln1_g; margs.ln1_b = ln1_b;
    margs.ln2_g = ln2_g; margs.ln2_b = ln2_b;
    margs.ln3_g = ln3_g; margs.ln3_b = ln3_b;
    margs.dw = dw; margs.db = db;
    margs.use_cache = use_cache;

    // Residency-safe grid: 2 blocks/CU (LB(256,2) caps VGPRs; 48KB LDS -> 3/CU).
    int dev = 0; hipGetDevice(&dev);
    int ncu = 0; hipDeviceGetAttribute(&ncu, hipDeviceAttributeMultiprocessorCount, dev);
    if (ncu <= 0) ncu = 256;
    int grid = 2 * ncu; if (grid > 512) grid = 512;

    mega<<<grid, 256, 0, stream>>>(margs);
}